// Round 2
// baseline (411.670 us; speedup 1.0000x reference)
//
#include <hip/hip_runtime.h>

// Problem constants (from reference)
#define BB 4
#define CC 256
#define HH 256
#define WW 256
#define HWV (HH * WW)          // 65536
#define N_BOX 64
#define SS 7
#define NPTS (SS * SS)         // 49
#define NROI (BB * N_BOX)      // 256
#define ROI_SCALE 0.25f

// ---------------------------------------------------------------------------
// Pass 1: transpose (B, C, H*W) -> (B, H*W, C) into workspace.
// 64x64 tile in LDS, float4 global loads and stores, stride-65 padding
// (2-way bank aliasing only -> free on gfx950).
// ---------------------------------------------------------------------------
__global__ __launch_bounds__(256) void transpose_kernel(
    const float* __restrict__ in,   // (B, C, HW)
    float* __restrict__ out)        // (B, HW, C)
{
    __shared__ float tile[64 * 65]; // [j(hw-local)][i(c-local)], row stride 65

    const int hw0 = blockIdx.x * 64;
    const int c0  = blockIdx.y * 64;
    const int b   = blockIdx.z;
    const int tid = threadIdx.x;

    // Load: 16 lanes x float4 cover 64 hw per c-row; 16 c-rows per k-step.
    {
        const int jq = tid & 15;   // hw quad index
        const int ir = tid >> 4;   // c-row base
        const float* inb = in + ((size_t)(b * CC + c0) << 16) + hw0;
        #pragma unroll
        for (int k = 0; k < 4; ++k) {
            const int i = ir + 16 * k;
            const float4 v = *(const float4*)(inb + ((size_t)i << 16) + jq * 4);
            tile[(jq * 4 + 0) * 65 + i] = v.x;
            tile[(jq * 4 + 1) * 65 + i] = v.y;
            tile[(jq * 4 + 2) * 65 + i] = v.z;
            tile[(jq * 4 + 3) * 65 + i] = v.w;
        }
    }
    __syncthreads();

    // Store: 16 lanes x float4 cover 64 c per hw-row.
    {
        const int iq = tid & 15;   // c quad index
        const int jr = tid >> 4;   // hw-row base
        float* outb = out + (((size_t)b << 16) + hw0) * CC + c0;
        #pragma unroll
        for (int k = 0; k < 4; ++k) {
            const int j = jr + 16 * k;
            float4 v;
            v.x = tile[j * 65 + iq * 4 + 0];
            v.y = tile[j * 65 + iq * 4 + 1];
            v.z = tile[j * 65 + iq * 4 + 2];
            v.w = tile[j * 65 + iq * 4 + 3];
            *(float4*)(outb + (size_t)j * CC + iq * 4) = v;
        }
    }
}

// ---------------------------------------------------------------------------
// Shared per-point precompute (offsets + validity-folded bilinear weights).
// ---------------------------------------------------------------------------
__device__ __forceinline__ void precompute_points(
    const float* __restrict__ rois, int r, int tid,
    int s_off[4][NPTS], float s_w[4][NPTS])
{
    if (tid < NPTS) {
        const float cx = rois[r * 5 + 0] * ROI_SCALE;
        const float cy = rois[r * 5 + 1] * ROI_SCALE;
        const float bw = rois[r * 5 + 2] * ROI_SCALE;
        const float bh = rois[r * 5 + 3] * ROI_SCALE;
        const float th = rois[r * 5 + 4];
        const float ct = cosf(th);
        const float st = sinf(th);

        const int py = tid / SS;
        const int px = tid - py * SS;
        const float lu = (px + 0.5f) / (float)SS - 0.5f;
        const float lv = (py + 0.5f) / (float)SS - 0.5f;
        const float u = lu * bw;
        const float v = lv * bh;
        const float x = cx + u * ct - v * st;
        const float y = cy + u * st + v * ct;

        const float x0f = floorf(x), y0f = floorf(y);
        const float x1f = x0f + 1.0f, y1f = y0f + 1.0f;
        const float wx1 = x - x0f, wx0 = 1.0f - wx1;
        const float wy1 = y - y0f, wy0 = 1.0f - wy1;

        const bool vx0 = (x0f >= 0.0f) && (x0f <= (float)(WW - 1));
        const bool vx1 = (x1f >= 0.0f) && (x1f <= (float)(WW - 1));
        const bool vy0 = (y0f >= 0.0f) && (y0f <= (float)(HH - 1));
        const bool vy1 = (y1f >= 0.0f) && (y1f <= (float)(HH - 1));

        const int x0c = min(max((int)x0f, 0), WW - 1);
        const int x1c = min(max((int)x1f, 0), WW - 1);
        const int y0c = min(max((int)y0f, 0), HH - 1);
        const int y1c = min(max((int)y1f, 0), HH - 1);

        s_off[0][tid] = y0c * WW + x0c;  s_w[0][tid] = (vx0 && vy0) ? wx0 * wy0 : 0.0f;
        s_off[1][tid] = y0c * WW + x1c;  s_w[1][tid] = (vx1 && vy0) ? wx1 * wy0 : 0.0f;
        s_off[2][tid] = y1c * WW + x0c;  s_w[2][tid] = (vx0 && vy1) ? wx0 * wy1 : 0.0f;
        s_off[3][tid] = y1c * WW + x1c;  s_w[3][tid] = (vx1 && vy1) ? wx1 * wy1 : 0.0f;
    }
}

// ---------------------------------------------------------------------------
// Pass 2: gather from channel-last feats_t. Block = (roi, 64-channel group).
// Reads are float4 across channels (256 B contiguous per point-group);
// output staged in LDS, written back perfectly coalesced.
// ---------------------------------------------------------------------------
#define CGP 64                  // channels per pass-2 block
#define NG2 (CC / CGP)          // 4
#define TSTRIDE 65              // LDS tile row stride (pad: (p + c) % 32 banking)

__global__ __launch_bounds__(256) void gather_cl_kernel(
    const float* __restrict__ ft,    // (B, HW, C) transposed feats
    const float* __restrict__ rois,
    float* __restrict__ out)         // (NROI, C, S, S)
{
    __shared__ int   s_off[4][NPTS];
    __shared__ float s_w[4][NPTS];
    __shared__ float t[NPTS * TSTRIDE];   // [p][c_local]

    const int r   = blockIdx.x;
    const int cg  = blockIdx.y;
    const int b   = r >> 6;
    const int tid = threadIdx.x;

    precompute_points(rois, r, tid, s_off, s_w);
    __syncthreads();

    const float* base = ft + ((size_t)b << 16) * CC + cg * CGP;

    // 49 points x 16 channel-quads = 784 work items.
    for (int w = tid; w < NPTS * (CGP / 4); w += 256) {
        const int p  = w >> 4;
        const int cq = w & 15;
        float4 acc = make_float4(0.f, 0.f, 0.f, 0.f);
        #pragma unroll
        for (int k = 0; k < 4; ++k) {
            const float4 v = *(const float4*)(base + (size_t)s_off[k][p] * CC + cq * 4);
            const float wk = s_w[k][p];
            acc.x += wk * v.x;
            acc.y += wk * v.y;
            acc.z += wk * v.z;
            acc.w += wk * v.w;
        }
        t[p * TSTRIDE + cq * 4 + 0] = acc.x;
        t[p * TSTRIDE + cq * 4 + 1] = acc.y;
        t[p * TSTRIDE + cq * 4 + 2] = acc.z;
        t[p * TSTRIDE + cq * 4 + 3] = acc.w;
    }
    __syncthreads();

    // Writeback: out[(r*C + cg*CGP + c)*49 + p] = base + j, j = c*49 + p — linear.
    float* ob = out + ((size_t)r * CC + (size_t)cg * CGP) * NPTS;
    for (int j = tid; j < CGP * NPTS; j += 256) {
        const int c = j / NPTS;
        const int p = j - c * NPTS;
        ob[j] = t[p * TSTRIDE + c];
    }
}

// ---------------------------------------------------------------------------
// Fallback (R1 kernel): single-pass scattered gather, used if ws too small.
// ---------------------------------------------------------------------------
__global__ __launch_bounds__(256) void rotated_roi_align_fallback(
    const float* __restrict__ feats,
    const float* __restrict__ rois,
    float* __restrict__ out)
{
    __shared__ int   s_off[4][NPTS];
    __shared__ float s_w[4][NPTS];

    const int r   = blockIdx.x;
    const int cq  = blockIdx.y;
    const int b   = r >> 6;
    const int tid = threadIdx.x;

    precompute_points(rois, r, tid, s_off, s_w);
    __syncthreads();

    const float* plane_base = feats + ((size_t)b * CC + (size_t)cq * 64) * HWV;
    float* ob = out + (size_t)r * CC * NPTS + (size_t)cq * 64 * NPTS;

    #pragma unroll 4
    for (int i = tid; i < 64 * NPTS; i += 256) {
        const int cl = i / NPTS;
        const int p  = i - cl * NPTS;
        const float* plane = plane_base + (size_t)cl * HWV;
        const float v0 = plane[s_off[0][p]];
        const float v1 = plane[s_off[1][p]];
        const float v2 = plane[s_off[2][p]];
        const float v3 = plane[s_off[3][p]];
        ob[i] = s_w[0][p] * v0 + s_w[1][p] * v1 + s_w[2][p] * v2 + s_w[3][p] * v3;
    }
}

extern "C" void kernel_launch(void* const* d_in, const int* in_sizes, int n_in,
                              void* d_out, int out_size, void* d_ws, size_t ws_size,
                              hipStream_t stream) {
    const float* feats = (const float*)d_in[0];
    const float* rois  = (const float*)d_in[1];
    float* out = (float*)d_out;

    const size_t need = (size_t)BB * CC * HWV * sizeof(float); // 256 MB

    if (ws_size >= need) {
        float* feats_t = (float*)d_ws;
        dim3 g1(HWV / 64, CC / 64, BB);       // 1024 x 4 x 4
        transpose_kernel<<<g1, 256, 0, stream>>>(feats, feats_t);
        dim3 g2(NROI, NG2);                   // 256 x 4
        gather_cl_kernel<<<g2, 256, 0, stream>>>(feats_t, rois, out);
    } else {
        dim3 grid(NROI, 4);
        rotated_roi_align_fallback<<<grid, 256, 0, stream>>>(feats, rois, out);
    }
}